// Round 3
// baseline (42.693 us; speedup 1.0000x reference)
//
#include <hip/hip_runtime.h>
#include <math.h>

// UnrolledMeanShift: B=2, D=32, H=W=256, K=5x5, 3 iterations.
// Channel-split: 2 threads per pixel (16 channels each) -> 2x waves for
// latency hiding. Scalar dot combined across the pair with one quad-perm DPP.
// patches constant across iters -> stage 20x20 halo tile ONCE in LDS as fp16.
// dist^2 = |p|^2 - 2 p.z + |z|^2 ; weight = exp2(A2*dot - sq[p] - zz).

typedef _Float16 h2 __attribute__((ext_vector_type(2)));
typedef _Float16 h8 __attribute__((ext_vector_type(8)));

constexpr int Dch  = 32;
constexpr int HH   = 256;
constexpr int WW   = 256;
constexpr int PADp = 2;
constexpr int BH   = 16;
constexpr int BW   = 16;
constexpr int TH   = BH + 2 * PADp;   // 20
constexpr int TWd  = BW + 2 * PADp;   // 20
constexpr int NPIX = TH * TWd;        // 400
constexpr int NCHK = 4;               // 4 chunks x 8 fp16 channels
constexpr int ITERS = 3;
constexpr int HWp  = HH * WW;
constexpr int NTHR = 512;             // 2 threads / pixel

__device__ __forceinline__ float fdot2f(h2 a, h2 b, float c) {
    return __builtin_amdgcn_fdot2(a, b, c, false);
}

__device__ __forceinline__ float EXP2F(float x) {
#if __has_builtin(__builtin_amdgcn_exp2f)
    return __builtin_amdgcn_exp2f(x);
#else
    return __expf(x * 0.69314718055994531f);
#endif
}

// value from lane^1 (quad_perm [1,0,3,2]) — pure VALU, no LDS pipe
__device__ __forceinline__ float qswap(float x) {
#if __has_builtin(__builtin_amdgcn_mov_dpp)
    return __int_as_float(
        __builtin_amdgcn_mov_dpp(__float_as_int(x), 0xB1, 0xF, 0xF, true));
#else
    return __shfl_xor(x, 1, 64);
#endif
}

__global__ __launch_bounds__(NTHR, 4)
void meanshift_kernel(const float* __restrict__ E,
                      const float* __restrict__ lbw,
                      float* __restrict__ out)
{
    __shared__ h8    tile[NCHK][NPIX];   // 25.6 KB
    __shared__ float sqv[NPIX];          // NC * |p|^2 (full 32-ch) per pixel

    const int b   = blockIdx.z;
    const int oh  = blockIdx.y * BH - PADp;
    const int ow  = blockIdx.x * BW - PADp;
    const int tid = threadIdx.x;
    const int half = tid & 1;            // which 16 channels
    const int pix  = tid >> 1;           // 0..255 pixel in tile
    const int px   = pix & (BW - 1);
    const int py   = pix >> 4;
    const int c0   = 2 * half;           // first of my two chunk planes

    const float bwv = log1pf(__expf(lbw[0]));   // softplus
    const float c2  = 1.0f / (2.0f * bwv * bwv);
    const float L2E = 1.44269504f;
    const float A2  = 2.0f * c2 * L2E;          // coef on p.z
    const float NC  = c2 * L2E;                 // coef on |p|^2, |z|^2

    const float* Eb = E + (size_t)b * Dch * HWp;

    // ---- stage halo tile into LDS as fp16 ----
    for (int job = tid; job < NCHK * NPIX; job += NTHR) {
        const int cc = job / NPIX;
        const int p  = job - cc * NPIX;
        const int tr = p / TWd;
        const int tc = p - tr * TWd;
        const int gh = oh + tr;
        const int gw = ow + tc;
        h8 v;
        if ((unsigned)gh < (unsigned)HH && (unsigned)gw < (unsigned)WW) {
            const float* p0 = Eb + (size_t)(8 * cc) * HWp + gh * WW + gw;
            #pragma unroll
            for (int k = 0; k < 8; ++k) v[k] = (_Float16)p0[k * HWp];
        } else {
            #pragma unroll
            for (int k = 0; k < 8; ++k) v[k] = (_Float16)0.f;
        }
        tile[cc][p] = v;
    }
    __syncthreads();

    // ---- precompute NC*|p|^2 per tile pixel ----
    for (int p = tid; p < NPIX; p += NTHR) {
        float a0 = 0.f, a1 = 0.f, a2 = 0.f, a3 = 0.f;
        #pragma unroll
        for (int c = 0; c < NCHK; ++c) {
            h8 v = tile[c][p];
            const h2* q = (const h2*)&v;
            a0 = fdot2f(q[0], q[0], a0);
            a1 = fdot2f(q[1], q[1], a1);
            a2 = fdot2f(q[2], q[2], a2);
            a3 = fdot2f(q[3], q[3], a3);
        }
        sqv[p] = ((a0 + a1) + (a2 + a3)) * NC;
    }
    __syncthreads();

    // ---- init z = own pixel, my 16 channels ----
    const int myp = (py + PADp) * TWd + (px + PADp);
    h2 z2[8];
    {
        h8 v0 = tile[c0][myp];
        h8 v1 = tile[c0 + 1][myp];
        const h2* q0 = (const h2*)&v0;
        const h2* q1 = (const h2*)&v1;
        #pragma unroll
        for (int k = 0; k < 4; ++k) { z2[k] = q0[k]; z2[4 + k] = q1[k]; }
    }
    float zz = sqv[myp];   // full 32-ch NC*|z|^2 for iteration 0

    float zf[16];
    #pragma unroll 1
    for (int it = 0; it < ITERS; ++it) {
        float num[16];
        #pragma unroll
        for (int d = 0; d < 16; ++d) num[d] = 0.f;
        float den = 0.f;

        #pragma unroll 1
        for (int di = 0; di < 5; ++di) {
            const int rowbase = (py + di) * TWd + px;
            #pragma unroll
            for (int dj = 0; dj < 5; ++dj) {
                const int np_ = rowbase + dj;
                h8 P0 = tile[c0][np_];
                h8 P1 = tile[c0 + 1][np_];
                const float sq = sqv[np_];
                const h2* q0 = (const h2*)&P0;
                const h2* q1 = (const h2*)&P1;
                float d0 = 0.f, d1 = 0.f, d2 = 0.f, d3 = 0.f;
                #pragma unroll
                for (int k = 0; k < 2; ++k) {
                    d0 = fdot2f(q0[k],     z2[k],     d0);
                    d1 = fdot2f(q0[2 + k], z2[2 + k], d1);
                    d2 = fdot2f(q1[k],     z2[4 + k], d2);
                    d3 = fdot2f(q1[2 + k], z2[6 + k], d3);
                }
                const float dpart = (d0 + d1) + (d2 + d3);   // my 16 channels
                const float dot   = dpart + qswap(dpart);     // full 32 (symmetric)
                const float w = EXP2F(fmaf(A2, dot, -(sq + zz)));
                den += w;
                const _Float16* e0 = (const _Float16*)&P0;
                const _Float16* e1 = (const _Float16*)&P1;
                #pragma unroll
                for (int k = 0; k < 8; ++k) {
                    num[k]     = fmaf((float)e0[k], w, num[k]);
                    num[8 + k] = fmaf((float)e1[k], w, num[8 + k]);
                }
            }
        }

        const float inv = 1.0f / (den + 1e-6f);
        #pragma unroll
        for (int d = 0; d < 16; ++d) zf[d] = num[d] * inv;

        if (it < ITERS - 1) {
            #pragma unroll
            for (int k = 0; k < 8; ++k)
                z2[k] = h2{(_Float16)zf[2 * k], (_Float16)zf[2 * k + 1]};
            float a0 = 0.f, a1 = 0.f;
            #pragma unroll
            for (int k = 0; k < 4; ++k) {
                a0 = fdot2f(z2[k],     z2[k],     a0);
                a1 = fdot2f(z2[4 + k], z2[4 + k], a1);
            }
            const float zzp = a0 + a1;
            zz = (zzp + qswap(zzp)) * NC;   // full 32-ch, symmetric
        }
    }

    // ---- write out: my 16 channels ----
    float* Ob = out + (size_t)b * Dch * HWp;
    const int off = (oh + PADp + py) * WW + (ow + PADp + px);
    #pragma unroll
    for (int k = 0; k < 16; ++k)
        Ob[(size_t)(16 * half + k) * HWp + off] = zf[k];
}

extern "C" void kernel_launch(void* const* d_in, const int* in_sizes, int n_in,
                              void* d_out, int out_size, void* d_ws, size_t ws_size,
                              hipStream_t stream) {
    const float* E   = (const float*)d_in[0];
    const float* lbw = (const float*)d_in[1];
    float* out       = (float*)d_out;

    const int B = in_sizes[0] / (Dch * HWp);       // = 2
    dim3 grid(WW / BW, HH / BH, B);                // (16,16,2) = 512 blocks
    dim3 block(NTHR, 1, 1);                        // 512 threads (2/pixel)
    hipLaunchKernelGGL(meanshift_kernel, grid, block, 0, stream, E, lbw, out);
}